// Round 5
// baseline (20547.984 us; speedup 1.0000x reference)
//
#include <hip/hip_runtime.h>
#include <hip/hip_fp16.h>

#define MM 2048
#define NN 2048
#define DD 512
#define NA 2049        // augmented dim (m+1 = n+1)
#define LDH 2056       // fp16 padded row stride (4112 B, 16B-aligned)
#define LDE 1024       // split-bf16 row stride ([hi(512) | lo(512)])
#define ITERS 100
#define NWG 256        // persistent grid: must be <= 256 CUs for co-residency
#define TPB 576        // 9 waves: 8 row-waves + 1 special/idle wave

typedef __attribute__((ext_vector_type(8))) short short8;
typedef __attribute__((ext_vector_type(4))) float f32x4;

__device__ __forceinline__ unsigned short f2bf(float x) {
    unsigned u = __builtin_bit_cast(unsigned, x);
    u += 0x7FFFu + ((u >> 16) & 1u);          // round-to-nearest-even
    return (unsigned short)(u >> 16);
}
__device__ __forceinline__ float bf2f(unsigned short h) {
    unsigned u = ((unsigned)h) << 16;
    return __builtin_bit_cast(float, u);
}
__device__ __forceinline__ void gload_lds16(const void* g, void* l) {
    __builtin_amdgcn_global_load_lds(
        (const __attribute__((address_space(1))) void*)g,
        (__attribute__((address_space(3))) void*)l, 16, 0, 0);
}

// ---------------------------------------------------------------------------
// fused init + split: blocks x<1024 split f32 -> bf16 hi|lo; x>=1024 init
// augmented row/col of K0, K0hT, Kreg + c=1 + barrier slots
// ---------------------------------------------------------------------------
__global__ __launch_bounds__(256) void init_split(const float* __restrict__ Q,
                                                  const float* __restrict__ Rm,
                                                  ushort* __restrict__ Qe,
                                                  ushort* __restrict__ Re,
                                                  float* __restrict__ Kreg,
                                                  _Float16* __restrict__ K0h,
                                                  _Float16* __restrict__ K0hT,
                                                  float* __restrict__ c,
                                                  unsigned* __restrict__ ctrl,
                                                  const float* __restrict__ zp) {
    if (blockIdx.x < 1024) {
        const float* src = blockIdx.y ? Rm : Q;
        ushort* dst = blockIdx.y ? Re : Qe;
        int e4 = blockIdx.x * 256 + threadIdx.x;    // float4 units
        int row = e4 >> 7;
        int c4 = (e4 & 127) * 4;
        float4 v = *(const float4*)(src + (size_t)row * DD + c4);
        ushort4 hi, lo;
        hi.x = f2bf(v.x); lo.x = f2bf(v.x - bf2f(hi.x));
        hi.y = f2bf(v.y); lo.y = f2bf(v.y - bf2f(hi.y));
        hi.z = f2bf(v.z); lo.z = f2bf(v.z - bf2f(hi.z));
        hi.w = f2bf(v.w); lo.w = f2bf(v.w - bf2f(hi.w));
        *(ushort4*)(dst + (size_t)row * LDE + c4) = hi;
        *(ushort4*)(dst + (size_t)row * LDE + 512 + c4) = lo;
    } else {
        float e5 = expf(zp[0] * 10.0f);   // exp(z/eps)
        int idx = (blockIdx.x - 1024) * 512 + blockIdx.y * 256 + threadIdx.x;
        for (int t = idx; t < NA; t += 1024) {
            if (t < 512) ctrl[t] = 0u;
            c[t] = 1.0f;
            Kreg[(size_t)2048 * NA + t] = e5;
            K0h [(size_t)2048 * LDH + t] = (_Float16)e5;
            K0hT[(size_t)2048 * LDH + t] = (_Float16)e5;
            if (t < MM) {
                Kreg[(size_t)t * NA + 2048] = e5;
                K0h [(size_t)t * LDH + 2048] = (_Float16)e5;
                K0hT[(size_t)t * LDH + 2048] = (_Float16)e5;
            }
        }
    }
}

// ---------------------------------------------------------------------------
// bf16 MFMA GEMM over K'=1024 (hi|lo concat) + exp epilogue.
// Writes f32 Kreg, fp16 K0h, AND fp16 K0hT (fused transpose: each lane's 4
// same-column acc values -> one 8B packed store).
// ---------------------------------------------------------------------------
__global__ __launch_bounds__(256, 2) void gemm_mfma(const ushort* __restrict__ Ae,
                                                    const ushort* __restrict__ Be,
                                                    float* __restrict__ Kreg,
                                                    _Float16* __restrict__ K0h,
                                                    _Float16* __restrict__ K0hT) {
    __shared__ ushort Als[64 * 32];
    __shared__ ushort Bls[128 * 32];
    const int tid = threadIdx.x;
    const int wid = tid >> 6, lane = tid & 63;
    const int row0 = blockIdx.y * 64, col0 = blockIdx.x * 128;
    const int wr = wid >> 1, wc = wid & 1;

    const int sr = lane >> 2, sc = (lane & 3) * 8;
    const ushort* gA  = Ae + (size_t)(row0 + wid * 16 + sr) * LDE + sc;
    const ushort* gB0 = Be + (size_t)(col0 + wid * 16 + sr) * LDE + sc;
    const ushort* gB1 = Be + (size_t)(col0 + 64 + wid * 16 + sr) * LDE + sc;
    ushort* lA  = &Als[wid * 16 * 32];
    ushort* lB0 = &Bls[wid * 16 * 32];
    ushort* lB1 = &Bls[(64 + wid * 16) * 32];

    f32x4 acc[2][4] = {};
    const int fr = lane & 15, fk = (lane >> 4) * 8;

    for (int k0 = 0; k0 < 1024; k0 += 32) {
        __syncthreads();
        gload_lds16(gA + k0, lA);
        gload_lds16(gB0 + k0, lB0);
        gload_lds16(gB1 + k0, lB1);
        __syncthreads();
        short8 a[2], b[4];
#pragma unroll
        for (int mi = 0; mi < 2; ++mi)
            a[mi] = *(const short8*)&Als[(wr * 32 + mi * 16 + fr) * 32 + fk];
#pragma unroll
        for (int ni = 0; ni < 4; ++ni)
            b[ni] = *(const short8*)&Bls[(wc * 64 + ni * 16 + fr) * 32 + fk];
#pragma unroll
        for (int mi = 0; mi < 2; ++mi)
#pragma unroll
            for (int ni = 0; ni < 4; ++ni)
                acc[mi][ni] = __builtin_amdgcn_mfma_f32_16x16x32_bf16(
                    a[mi], b[ni], acc[mi][ni], 0, 0, 0);
    }

#pragma unroll
    for (int mi = 0; mi < 2; ++mi)
#pragma unroll
        for (int ni = 0; ni < 4; ++ni) {
            const int rowb = row0 + wr * 32 + mi * 16 + (lane >> 4) * 4;
            const int col  = col0 + wc * 64 + ni * 16 + fr;
            union { ushort4 u; _Float16 h[4]; } tp;
#pragma unroll
            for (int q = 0; q < 4; ++q) {
                float v = expf(acc[mi][ni][q] * 10.0f);
                Kreg[(size_t)(rowb + q) * NA + col] = v;
                _Float16 hv = (_Float16)v;
                K0h[(size_t)(rowb + q) * LDH + col] = hv;
                tp.h[q] = hv;
            }
            *(ushort4*)(K0hT + (size_t)col * LDH + rowb) = tp.u;  // 8B, aligned
        }
}

// ---------------------------------------------------------------------------
// persistent Sinkhorn loop: K rows cached in LDS (fp16), slotted grid barrier
// with wave-level release polling; fused finalize at the end.
// ---------------------------------------------------------------------------
__device__ __forceinline__ void grid_barrier(unsigned* slot, int lane) {
    __syncthreads();
    if (threadIdx.x == 0)
        __hip_atomic_fetch_add(slot, 1u, __ATOMIC_ACQ_REL, __HIP_MEMORY_SCOPE_AGENT);
    if (lane == 0) {
        while (__hip_atomic_load(slot, __ATOMIC_ACQUIRE, __HIP_MEMORY_SCOPE_AGENT)
               != (unsigned)NWG)
            __builtin_amdgcn_s_sleep(1);
    }
    __threadfence();   // wave-wide acquire after lane-0 observed the release
}

__global__ __launch_bounds__(TPB) void sinkhorn_persist(
    const _Float16* __restrict__ K0h, const _Float16* __restrict__ K0hT,
    float* r, float* c, unsigned* slots, const float* __restrict__ zp,
    float* __restrict__ Kreg, float* __restrict__ P)
{
    __shared__ _Float16 kls[2][8][2048];     // exactly 64 KB
    const int wave = threadIdx.x / 64, lane = threadIdx.x & 63;
    const int row = blockIdx.x * 8 + wave;   // valid for wave < 8 (rows 0..2047)
    const float e5 = expf(zp[0] * 10.0f);
    const bool rowwave = (wave < 8);
    const bool special = (blockIdx.x == 0 && wave == 8);   // handles row 2048

    // preload this WG's 8 rows of K0 and K0^T into LDS (fp16)
    if (rowwave) {
        const _Float16* ga = K0h  + (size_t)row * LDH;
        const _Float16* gb = K0hT + (size_t)row * LDH;
#pragma unroll
        for (int s = 0; s < 4; ++s) {
            const int j = (s * 64 + lane) * 8;
            *(uint4*)&kls[0][wave][j] = *(const uint4*)(ga + j);
            *(uint4*)&kls[1][wave][j] = *(const uint4*)(gb + j);
        }
    }
    // (grid_barrier's __syncthreads covers the LDS preload fence)

    for (int it = 0; it < ITERS; ++it) {
        // ---- phase 1: r = 1 / (K0 c) ----
        if (rowwave) {
            float s0 = 0.f, s1 = 0.f, s2 = 0.f, s3 = 0.f;
#pragma unroll
            for (int s = 0; s < 4; ++s) {
                const int j = (s * 64 + lane) * 8;
                union { uint4 u; _Float16 h[8]; } kv;
                kv.u = *(const uint4*)&kls[0][wave][j];
                float4 c0 = *(const float4*)(c + j);
                float4 c1 = *(const float4*)(c + j + 4);
                s0 += (float)kv.h[0] * c0.x + (float)kv.h[4] * c1.x;
                s1 += (float)kv.h[1] * c0.y + (float)kv.h[5] * c1.y;
                s2 += (float)kv.h[2] * c0.z + (float)kv.h[6] * c1.z;
                s3 += (float)kv.h[3] * c0.w + (float)kv.h[7] * c1.w;
            }
            float sum = (s0 + s1) + (s2 + s3);
#pragma unroll
            for (int off = 32; off; off >>= 1) sum += __shfl_xor(sum, off, 64);
            if (lane == 0) r[row] = 1.0f / (sum + e5 * c[2048]);
        } else if (special) {
            float t = 0.f;
#pragma unroll
            for (int s = 0; s < 4; ++s) {
                const int j = (s * 64 + lane) * 8;
                float4 a = *(const float4*)(c + j);
                float4 b = *(const float4*)(c + j + 4);
                t += (a.x + a.y) + (a.z + a.w) + (b.x + b.y) + (b.z + b.w);
            }
#pragma unroll
            for (int off = 32; off; off >>= 1) t += __shfl_xor(t, off, 64);
            if (lane == 0) r[2048] = 1.0f / (e5 * (t + c[2048]));
        }
        grid_barrier(&slots[2 * it], lane);

        // ---- phase 2: c = 1 / (K0^T r) ----
        if (rowwave) {
            float s0 = 0.f, s1 = 0.f, s2 = 0.f, s3 = 0.f;
#pragma unroll
            for (int s = 0; s < 4; ++s) {
                const int j = (s * 64 + lane) * 8;
                union { uint4 u; _Float16 h[8]; } kv;
                kv.u = *(const uint4*)&kls[1][wave][j];
                float4 c0 = *(const float4*)(r + j);
                float4 c1 = *(const float4*)(r + j + 4);
                s0 += (float)kv.h[0] * c0.x + (float)kv.h[4] * c1.x;
                s1 += (float)kv.h[1] * c0.y + (float)kv.h[5] * c1.y;
                s2 += (float)kv.h[2] * c0.z + (float)kv.h[6] * c1.z;
                s3 += (float)kv.h[3] * c0.w + (float)kv.h[7] * c1.w;
            }
            float sum = (s0 + s1) + (s2 + s3);
#pragma unroll
            for (int off = 32; off; off >>= 1) sum += __shfl_xor(sum, off, 64);
            if (lane == 0) c[row] = 1.0f / (sum + e5 * r[2048]);
        } else if (special) {
            float t = 0.f;
#pragma unroll
            for (int s = 0; s < 4; ++s) {
                const int j = (s * 64 + lane) * 8;
                float4 a = *(const float4*)(r + j);
                float4 b = *(const float4*)(r + j + 4);
                t += (a.x + a.y) + (a.z + a.w) + (b.x + b.y) + (b.z + b.w);
            }
#pragma unroll
            for (int off = 32; off; off >>= 1) t += __shfl_xor(t, off, 64);
            if (lane == 0) c[2048] = 1.0f / (e5 * (t + r[2048]));
        }
        grid_barrier(&slots[2 * it + 1], lane);
    }

    // ---- fused finalize: K = diag(r) K0 diag(c), P = K[:M,:N] ----
    const int frow = blockIdx.x * 9 + wave;          // 2304 waves >= 2049 rows
    if (frow < NA) {
        const float rs = r[frow];
        float* krow = Kreg + (size_t)frow * NA;
        float* prow = P + (size_t)frow * NN;
        if (frow < MM) {
            for (int col = lane; col < NN; col += 64) {
                float v = krow[col] * rs * c[col];
                krow[col] = v;
                prow[col] = v;
            }
            if (lane == 0) krow[2048] = krow[2048] * rs * c[2048];
        } else {
            for (int col = lane; col < NA; col += 64)
                krow[col] = krow[col] * rs * c[col];
        }
    }
}

// ---------------------------------------------------------------------------
extern "C" void kernel_launch(void* const* d_in, const int* in_sizes, int n_in,
                              void* d_out, int out_size, void* d_ws, size_t ws_size,
                              hipStream_t stream) {
    const float* Q  = (const float*)d_in[0];
    const float* Rm = (const float*)d_in[1];
    const float* zp = (const float*)d_in[2];

    float* P    = (float*)d_out;
    float* Kreg = P + (size_t)MM * NN;

    ushort* Qe = (ushort*)d_out;                 // staged in P region (dead by finalize)
    ushort* Re = Qe + (size_t)2048 * LDE;

    char* ws = (char*)d_ws;
    const size_t HBYTES = 8425728;               // NA*LDH*2 rounded to 256
    _Float16* K0h  = (_Float16*)ws;
    _Float16* K0hT = (_Float16*)(ws + HBYTES);
    float* c = (float*)(ws + 2 * HBYTES);
    float* r = c + 2560;
    unsigned* ctrl = (unsigned*)(r + 2560);
    unsigned* slots = ctrl;                      // 200 slots used, zeroed by init

    init_split<<<dim3(1026, 2), dim3(256), 0, stream>>>(Q, Rm, Qe, Re, Kreg,
                                                        K0h, K0hT, c, ctrl, zp);
    gemm_mfma<<<dim3(16, 32), dim3(256), 0, stream>>>(Qe, Re, Kreg, K0h, K0hT);
    sinkhorn_persist<<<dim3(NWG), dim3(TPB), 0, stream>>>(K0h, K0hT, r, c,
                                                          slots, zp, Kreg, P);
}

// Round 6
// 3017.201 us; speedup vs baseline: 6.8103x; 6.8103x over previous
//
#include <hip/hip_runtime.h>
#include <hip/hip_fp16.h>

#define MM 2048
#define NN 2048
#define DD 512
#define NA 2049        // augmented dim (m+1 = n+1)
#define LDH 2056       // fp16 padded row stride (4112 B, 16B-aligned)
#define LDE 1024       // split-bf16 row stride ([hi(512) | lo(512)])
#define ITERS 100
#define NWG 256        // persistent grid: <= 256 CUs -> co-resident
#define TPB 576        // 9 waves: 8 row-waves + 1 special/finalize wave

typedef __attribute__((ext_vector_type(8))) short short8;
typedef __attribute__((ext_vector_type(4))) float f32x4;

__device__ __forceinline__ unsigned short f2bf(float x) {
    unsigned u = __builtin_bit_cast(unsigned, x);
    u += 0x7FFFu + ((u >> 16) & 1u);          // round-to-nearest-even
    return (unsigned short)(u >> 16);
}
__device__ __forceinline__ float bf2f(unsigned short h) {
    unsigned u = ((unsigned)h) << 16;
    return __builtin_bit_cast(float, u);
}
__device__ __forceinline__ void gload_lds16(const void* g, void* l) {
    __builtin_amdgcn_global_load_lds(
        (const __attribute__((address_space(1))) void*)g,
        (__attribute__((address_space(3))) void*)l, 16, 0, 0);
}

// ---------------------------------------------------------------------------
// fused init + split: blocks x<1024 split f32 -> bf16 hi|lo; x>=1024 init
// augmented row/col of K0, K0hT, Kreg + c=1 + barrier slots
// ---------------------------------------------------------------------------
__global__ __launch_bounds__(256) void init_split(const float* __restrict__ Q,
                                                  const float* __restrict__ Rm,
                                                  ushort* __restrict__ Qe,
                                                  ushort* __restrict__ Re,
                                                  float* __restrict__ Kreg,
                                                  _Float16* __restrict__ K0h,
                                                  _Float16* __restrict__ K0hT,
                                                  float* __restrict__ c,
                                                  unsigned* __restrict__ ctrl,
                                                  const float* __restrict__ zp) {
    if (blockIdx.x < 1024) {
        const float* src = blockIdx.y ? Rm : Q;
        ushort* dst = blockIdx.y ? Re : Qe;
        int e4 = blockIdx.x * 256 + threadIdx.x;    // float4 units
        int row = e4 >> 7;
        int c4 = (e4 & 127) * 4;
        float4 v = *(const float4*)(src + (size_t)row * DD + c4);
        ushort4 hi, lo;
        hi.x = f2bf(v.x); lo.x = f2bf(v.x - bf2f(hi.x));
        hi.y = f2bf(v.y); lo.y = f2bf(v.y - bf2f(hi.y));
        hi.z = f2bf(v.z); lo.z = f2bf(v.z - bf2f(hi.z));
        hi.w = f2bf(v.w); lo.w = f2bf(v.w - bf2f(hi.w));
        *(ushort4*)(dst + (size_t)row * LDE + c4) = hi;
        *(ushort4*)(dst + (size_t)row * LDE + 512 + c4) = lo;
    } else {
        float e5 = expf(zp[0] * 10.0f);   // exp(z/eps)
        int idx = (blockIdx.x - 1024) * 512 + blockIdx.y * 256 + threadIdx.x;
        for (int t = idx; t < NA; t += 1024) {
            if (t < 512) ctrl[t] = 0u;
            c[t] = 1.0f;
            Kreg[(size_t)2048 * NA + t] = e5;
            K0h [(size_t)2048 * LDH + t] = (_Float16)e5;
            K0hT[(size_t)2048 * LDH + t] = (_Float16)e5;
            if (t < MM) {
                Kreg[(size_t)t * NA + 2048] = e5;
                K0h [(size_t)t * LDH + 2048] = (_Float16)e5;
                K0hT[(size_t)t * LDH + 2048] = (_Float16)e5;
            }
        }
    }
}

// ---------------------------------------------------------------------------
// bf16 MFMA GEMM over K'=1024 (hi|lo concat) + exp epilogue.
// Writes f32 Kreg, fp16 K0h, AND fp16 K0hT (fused transpose: each lane's 4
// same-column acc values -> one 8B packed store).
// ---------------------------------------------------------------------------
__global__ __launch_bounds__(256, 2) void gemm_mfma(const ushort* __restrict__ Ae,
                                                    const ushort* __restrict__ Be,
                                                    float* __restrict__ Kreg,
                                                    _Float16* __restrict__ K0h,
                                                    _Float16* __restrict__ K0hT) {
    __shared__ ushort Als[64 * 32];
    __shared__ ushort Bls[128 * 32];
    const int tid = threadIdx.x;
    const int wid = tid >> 6, lane = tid & 63;
    const int row0 = blockIdx.y * 64, col0 = blockIdx.x * 128;
    const int wr = wid >> 1, wc = wid & 1;

    const int sr = lane >> 2, sc = (lane & 3) * 8;
    const ushort* gA  = Ae + (size_t)(row0 + wid * 16 + sr) * LDE + sc;
    const ushort* gB0 = Be + (size_t)(col0 + wid * 16 + sr) * LDE + sc;
    const ushort* gB1 = Be + (size_t)(col0 + 64 + wid * 16 + sr) * LDE + sc;
    ushort* lA  = &Als[wid * 16 * 32];
    ushort* lB0 = &Bls[wid * 16 * 32];
    ushort* lB1 = &Bls[(64 + wid * 16) * 32];

    f32x4 acc[2][4] = {};
    const int fr = lane & 15, fk = (lane >> 4) * 8;

    for (int k0 = 0; k0 < 1024; k0 += 32) {
        __syncthreads();
        gload_lds16(gA + k0, lA);
        gload_lds16(gB0 + k0, lB0);
        gload_lds16(gB1 + k0, lB1);
        __syncthreads();
        short8 a[2], b[4];
#pragma unroll
        for (int mi = 0; mi < 2; ++mi)
            a[mi] = *(const short8*)&Als[(wr * 32 + mi * 16 + fr) * 32 + fk];
#pragma unroll
        for (int ni = 0; ni < 4; ++ni)
            b[ni] = *(const short8*)&Bls[(wc * 64 + ni * 16 + fr) * 32 + fk];
#pragma unroll
        for (int mi = 0; mi < 2; ++mi)
#pragma unroll
            for (int ni = 0; ni < 4; ++ni)
                acc[mi][ni] = __builtin_amdgcn_mfma_f32_16x16x32_bf16(
                    a[mi], b[ni], acc[mi][ni], 0, 0, 0);
    }

#pragma unroll
    for (int mi = 0; mi < 2; ++mi)
#pragma unroll
        for (int ni = 0; ni < 4; ++ni) {
            const int rowb = row0 + wr * 32 + mi * 16 + (lane >> 4) * 4;
            const int col  = col0 + wc * 64 + ni * 16 + fr;
            union { ushort4 u; _Float16 h[4]; } tp;
#pragma unroll
            for (int q = 0; q < 4; ++q) {
                float v = expf(acc[mi][ni][q] * 10.0f);
                Kreg[(size_t)(rowb + q) * NA + col] = v;
                _Float16 hv = (_Float16)v;
                K0h[(size_t)(rowb + q) * LDH + col] = hv;
                tp.h[q] = hv;
            }
            *(ushort4*)(K0hT + (size_t)col * LDH + rowb) = tp.u;  // 8B, aligned
        }
}

// ---------------------------------------------------------------------------
// persistent Sinkhorn loop: K rows cached in LDS (fp16); round-3 proven
// grid barrier (single thread-0 arrive+poll, __syncthreads broadcast);
// fused finalize at the end.
// ---------------------------------------------------------------------------
__device__ __forceinline__ void grid_barrier(unsigned* slot) {
    __syncthreads();
    if (threadIdx.x == 0) {
        __hip_atomic_fetch_add(slot, 1u, __ATOMIC_ACQ_REL, __HIP_MEMORY_SCOPE_AGENT);
        while (__hip_atomic_load(slot, __ATOMIC_ACQUIRE, __HIP_MEMORY_SCOPE_AGENT)
               != (unsigned)NWG)
            __builtin_amdgcn_s_sleep(1);
    }
    __syncthreads();
}

__global__ __launch_bounds__(TPB) void sinkhorn_persist(
    const _Float16* __restrict__ K0h, const _Float16* __restrict__ K0hT,
    float* r, float* c, unsigned* slots, const float* __restrict__ zp,
    float* __restrict__ Kreg, float* __restrict__ P)
{
    __shared__ _Float16 kls[2][8][2048];     // exactly 64 KB
    const int wave = threadIdx.x / 64, lane = threadIdx.x & 63;
    const int row = blockIdx.x * 8 + wave;   // valid for wave < 8 (rows 0..2047)
    const float e5 = expf(zp[0] * 10.0f);
    const bool rowwave = (wave < 8);
    const bool special = (blockIdx.x == 0 && wave == 8);   // handles row 2048

    // preload this WG's 8 rows of K0 and K0^T into LDS (fp16)
    if (rowwave) {
        const _Float16* ga = K0h  + (size_t)row * LDH;
        const _Float16* gb = K0hT + (size_t)row * LDH;
#pragma unroll
        for (int s = 0; s < 4; ++s) {
            const int j = (s * 64 + lane) * 8;
            *(uint4*)&kls[0][wave][j] = *(const uint4*)(ga + j);
            *(uint4*)&kls[1][wave][j] = *(const uint4*)(gb + j);
        }
    }
    // first grid_barrier's __syncthreads covers the LDS preload

    for (int it = 0; it < ITERS; ++it) {
        // ---- phase 1: r = 1 / (K0 c) ----
        if (rowwave) {
            float s0 = 0.f, s1 = 0.f, s2 = 0.f, s3 = 0.f;
#pragma unroll
            for (int s = 0; s < 4; ++s) {
                const int j = (s * 64 + lane) * 8;
                union { uint4 u; _Float16 h[8]; } kv;
                kv.u = *(const uint4*)&kls[0][wave][j];
                float4 c0 = *(const float4*)(c + j);
                float4 c1 = *(const float4*)(c + j + 4);
                s0 += (float)kv.h[0] * c0.x + (float)kv.h[4] * c1.x;
                s1 += (float)kv.h[1] * c0.y + (float)kv.h[5] * c1.y;
                s2 += (float)kv.h[2] * c0.z + (float)kv.h[6] * c1.z;
                s3 += (float)kv.h[3] * c0.w + (float)kv.h[7] * c1.w;
            }
            float sum = (s0 + s1) + (s2 + s3);
#pragma unroll
            for (int off = 32; off; off >>= 1) sum += __shfl_xor(sum, off, 64);
            if (lane == 0) r[row] = 1.0f / (sum + e5 * c[2048]);
        } else if (special) {
            float t = 0.f;
#pragma unroll
            for (int s = 0; s < 4; ++s) {
                const int j = (s * 64 + lane) * 8;
                float4 a = *(const float4*)(c + j);
                float4 b = *(const float4*)(c + j + 4);
                t += (a.x + a.y) + (a.z + a.w) + (b.x + b.y) + (b.z + b.w);
            }
#pragma unroll
            for (int off = 32; off; off >>= 1) t += __shfl_xor(t, off, 64);
            if (lane == 0) r[2048] = 1.0f / (e5 * (t + c[2048]));
        }
        grid_barrier(&slots[2 * it]);

        // ---- phase 2: c = 1 / (K0^T r) ----
        if (rowwave) {
            float s0 = 0.f, s1 = 0.f, s2 = 0.f, s3 = 0.f;
#pragma unroll
            for (int s = 0; s < 4; ++s) {
                const int j = (s * 64 + lane) * 8;
                union { uint4 u; _Float16 h[8]; } kv;
                kv.u = *(const uint4*)&kls[1][wave][j];
                float4 c0 = *(const float4*)(r + j);
                float4 c1 = *(const float4*)(r + j + 4);
                s0 += (float)kv.h[0] * c0.x + (float)kv.h[4] * c1.x;
                s1 += (float)kv.h[1] * c0.y + (float)kv.h[5] * c1.y;
                s2 += (float)kv.h[2] * c0.z + (float)kv.h[6] * c1.z;
                s3 += (float)kv.h[3] * c0.w + (float)kv.h[7] * c1.w;
            }
            float sum = (s0 + s1) + (s2 + s3);
#pragma unroll
            for (int off = 32; off; off >>= 1) sum += __shfl_xor(sum, off, 64);
            if (lane == 0) c[row] = 1.0f / (sum + e5 * r[2048]);
        } else if (special) {
            float t = 0.f;
#pragma unroll
            for (int s = 0; s < 4; ++s) {
                const int j = (s * 64 + lane) * 8;
                float4 a = *(const float4*)(r + j);
                float4 b = *(const float4*)(r + j + 4);
                t += (a.x + a.y) + (a.z + a.w) + (b.x + b.y) + (b.z + b.w);
            }
#pragma unroll
            for (int off = 32; off; off >>= 1) t += __shfl_xor(t, off, 64);
            if (lane == 0) c[2048] = 1.0f / (e5 * (t + r[2048]));
        }
        grid_barrier(&slots[2 * it + 1]);
    }

    // ---- fused finalize: K = diag(r) K0 diag(c), P = K[:M,:N] ----
    const int frow = blockIdx.x * 9 + wave;          // 2304 waves >= 2049 rows
    if (frow < NA) {
        const float rs = r[frow];
        float* krow = Kreg + (size_t)frow * NA;
        float* prow = P + (size_t)frow * NN;
        if (frow < MM) {
            for (int col = lane; col < NN; col += 64) {
                float v = krow[col] * rs * c[col];
                krow[col] = v;
                prow[col] = v;
            }
            if (lane == 0) krow[2048] = krow[2048] * rs * c[2048];
        } else {
            for (int col = lane; col < NA; col += 64)
                krow[col] = krow[col] * rs * c[col];
        }
    }
}

// ---------------------------------------------------------------------------
extern "C" void kernel_launch(void* const* d_in, const int* in_sizes, int n_in,
                              void* d_out, int out_size, void* d_ws, size_t ws_size,
                              hipStream_t stream) {
    const float* Q  = (const float*)d_in[0];
    const float* Rm = (const float*)d_in[1];
    const float* zp = (const float*)d_in[2];

    float* P    = (float*)d_out;
    float* Kreg = P + (size_t)MM * NN;

    ushort* Qe = (ushort*)d_out;                 // staged in P region (dead by finalize)
    ushort* Re = Qe + (size_t)2048 * LDE;

    char* ws = (char*)d_ws;
    const size_t HBYTES = 8425728;               // NA*LDH*2 rounded to 256
    _Float16* K0h  = (_Float16*)ws;
    _Float16* K0hT = (_Float16*)(ws + HBYTES);
    float* c = (float*)(ws + 2 * HBYTES);
    float* r = c + 2560;
    unsigned* ctrl = (unsigned*)(r + 2560);
    unsigned* slots = ctrl;                      // 200 slots used, zeroed by init

    init_split<<<dim3(1026, 2), dim3(256), 0, stream>>>(Q, Rm, Qe, Re, Kreg,
                                                        K0h, K0hT, c, ctrl, zp);
    gemm_mfma<<<dim3(16, 32), dim3(256), 0, stream>>>(Qe, Re, Kreg, K0h, K0hT);
    sinkhorn_persist<<<dim3(NWG), dim3(TPB), 0, stream>>>(K0h, K0hT, r, c,
                                                          slots, zp, Kreg, P);
}

// Round 7
// 109.934 us; speedup vs baseline: 186.9124x; 27.4456x over previous
//
#include <hip/hip_runtime.h>
#include <hip/hip_fp16.h>

#define MM 2048
#define NN 2048
#define DD 512
#define NA 2049        // augmented dim (m+1 = n+1)
#define LDH 2056       // fp16 padded row stride (4112 B, 16B-aligned)
#define LDE 1024       // split-bf16 row stride ([hi(512) | lo(512)])
#define ITERS 100
#define NWG 257        // persistent grid (round-3 proven config)
#define TPB 512

typedef __attribute__((ext_vector_type(8))) short short8;
typedef __attribute__((ext_vector_type(4))) float f32x4;

__device__ __forceinline__ unsigned short f2bf(float x) {
    unsigned u = __builtin_bit_cast(unsigned, x);
    u += 0x7FFFu + ((u >> 16) & 1u);          // round-to-nearest-even
    return (unsigned short)(u >> 16);
}
__device__ __forceinline__ float bf2f(unsigned short h) {
    unsigned u = ((unsigned)h) << 16;
    return __builtin_bit_cast(float, u);
}
__device__ __forceinline__ void gload_lds16(const void* g, void* l) {
    __builtin_amdgcn_global_load_lds(
        (const __attribute__((address_space(1))) void*)g,
        (__attribute__((address_space(3))) void*)l, 16, 0, 0);
}

// ---------------------------------------------------------------------------
// fused init + split: blocks x<1024 split f32 -> bf16 hi|lo; x>=1024 init
// augmented row/col of K0, K0hT, Kreg + c=1 + barrier slots/chg flags
// ---------------------------------------------------------------------------
__global__ __launch_bounds__(256) void init_split(const float* __restrict__ Q,
                                                  const float* __restrict__ Rm,
                                                  ushort* __restrict__ Qe,
                                                  ushort* __restrict__ Re,
                                                  float* __restrict__ Kreg,
                                                  _Float16* __restrict__ K0h,
                                                  _Float16* __restrict__ K0hT,
                                                  float* __restrict__ c,
                                                  unsigned* __restrict__ ctrl,
                                                  const float* __restrict__ zp) {
    if (blockIdx.x < 1024) {
        const float* src = blockIdx.y ? Rm : Q;
        ushort* dst = blockIdx.y ? Re : Qe;
        int e4 = blockIdx.x * 256 + threadIdx.x;    // float4 units
        int row = e4 >> 7;
        int c4 = (e4 & 127) * 4;
        float4 v = *(const float4*)(src + (size_t)row * DD + c4);
        ushort4 hi, lo;
        hi.x = f2bf(v.x); lo.x = f2bf(v.x - bf2f(hi.x));
        hi.y = f2bf(v.y); lo.y = f2bf(v.y - bf2f(hi.y));
        hi.z = f2bf(v.z); lo.z = f2bf(v.z - bf2f(hi.z));
        hi.w = f2bf(v.w); lo.w = f2bf(v.w - bf2f(hi.w));
        *(ushort4*)(dst + (size_t)row * LDE + c4) = hi;
        *(ushort4*)(dst + (size_t)row * LDE + 512 + c4) = lo;
    } else {
        float e5 = expf(zp[0] * 10.0f);   // exp(z/eps)
        int idx = (blockIdx.x - 1024) * 512 + blockIdx.y * 256 + threadIdx.x;
        for (int t = idx; t < NA; t += 1024) {
            if (t < 512) ctrl[t] = 0u;
            c[t] = 1.0f;
            Kreg[(size_t)2048 * NA + t] = e5;
            K0h [(size_t)2048 * LDH + t] = (_Float16)e5;
            K0hT[(size_t)2048 * LDH + t] = (_Float16)e5;
            if (t < MM) {
                Kreg[(size_t)t * NA + 2048] = e5;
                K0h [(size_t)t * LDH + 2048] = (_Float16)e5;
                K0hT[(size_t)t * LDH + 2048] = (_Float16)e5;
            }
        }
    }
}

// ---------------------------------------------------------------------------
// bf16 MFMA GEMM over K'=1024 (hi|lo concat) + exp epilogue.
// Writes f32 Kreg, fp16 K0h, AND fp16 K0hT (fused transpose: each lane's 4
// same-column acc values -> one 8B packed store).  [verified rounds 5-6]
// ---------------------------------------------------------------------------
__global__ __launch_bounds__(256, 2) void gemm_mfma(const ushort* __restrict__ Ae,
                                                    const ushort* __restrict__ Be,
                                                    float* __restrict__ Kreg,
                                                    _Float16* __restrict__ K0h,
                                                    _Float16* __restrict__ K0hT) {
    __shared__ ushort Als[64 * 32];
    __shared__ ushort Bls[128 * 32];
    const int tid = threadIdx.x;
    const int wid = tid >> 6, lane = tid & 63;
    const int row0 = blockIdx.y * 64, col0 = blockIdx.x * 128;
    const int wr = wid >> 1, wc = wid & 1;

    const int sr = lane >> 2, sc = (lane & 3) * 8;
    const ushort* gA  = Ae + (size_t)(row0 + wid * 16 + sr) * LDE + sc;
    const ushort* gB0 = Be + (size_t)(col0 + wid * 16 + sr) * LDE + sc;
    const ushort* gB1 = Be + (size_t)(col0 + 64 + wid * 16 + sr) * LDE + sc;
    ushort* lA  = &Als[wid * 16 * 32];
    ushort* lB0 = &Bls[wid * 16 * 32];
    ushort* lB1 = &Bls[(64 + wid * 16) * 32];

    f32x4 acc[2][4] = {};
    const int fr = lane & 15, fk = (lane >> 4) * 8;

    for (int k0 = 0; k0 < 1024; k0 += 32) {
        __syncthreads();
        gload_lds16(gA + k0, lA);
        gload_lds16(gB0 + k0, lB0);
        gload_lds16(gB1 + k0, lB1);
        __syncthreads();
        short8 a[2], b[4];
#pragma unroll
        for (int mi = 0; mi < 2; ++mi)
            a[mi] = *(const short8*)&Als[(wr * 32 + mi * 16 + fr) * 32 + fk];
#pragma unroll
        for (int ni = 0; ni < 4; ++ni)
            b[ni] = *(const short8*)&Bls[(wc * 64 + ni * 16 + fr) * 32 + fk];
#pragma unroll
        for (int mi = 0; mi < 2; ++mi)
#pragma unroll
            for (int ni = 0; ni < 4; ++ni)
                acc[mi][ni] = __builtin_amdgcn_mfma_f32_16x16x32_bf16(
                    a[mi], b[ni], acc[mi][ni], 0, 0, 0);
    }

#pragma unroll
    for (int mi = 0; mi < 2; ++mi)
#pragma unroll
        for (int ni = 0; ni < 4; ++ni) {
            const int rowb = row0 + wr * 32 + mi * 16 + (lane >> 4) * 4;
            const int col  = col0 + wc * 64 + ni * 16 + fr;
            union { ushort4 u; _Float16 h[4]; } tp;
#pragma unroll
            for (int q = 0; q < 4; ++q) {
                float v = expf(acc[mi][ni][q] * 10.0f);
                Kreg[(size_t)(rowb + q) * NA + col] = v;
                _Float16 hv = (_Float16)v;
                K0h[(size_t)(rowb + q) * LDH + col] = hv;
                tp.h[q] = hv;
            }
            *(ushort4*)(K0hT + (size_t)col * LDH + rowb) = tp.u;  // 8B, aligned
        }
}

// ---------------------------------------------------------------------------
// persistent Sinkhorn loop — BYTE-EXACT round-3 kernel (proven 75 us):
// one wave per row, global K-row reads, slotted grid barrier, per-iter check
// ---------------------------------------------------------------------------
__device__ __forceinline__ void grid_barrier(unsigned* slot) {
    __syncthreads();
    if (threadIdx.x == 0) {
        __hip_atomic_fetch_add(slot, 1u, __ATOMIC_ACQ_REL, __HIP_MEMORY_SCOPE_AGENT);
        while (__hip_atomic_load(slot, __ATOMIC_ACQUIRE, __HIP_MEMORY_SCOPE_AGENT)
               != (unsigned)NWG)
            __builtin_amdgcn_s_sleep(1);
    }
    __syncthreads();
}

__device__ __forceinline__ float rowdot(const _Float16* __restrict__ Krow,
                                        const float* v, int lane) {
    float sum = 0.0f;
#pragma unroll
    for (int s = 0; s < 4; ++s) {
        const int j = (s * 64 + lane) * 8;
        union { uint4 u; _Float16 h[8]; } kv;
        kv.u = *(const uint4*)(Krow + j);
        float4 c0 = *(const float4*)(v + j);
        float4 c1 = *(const float4*)(v + j + 4);
        sum += (float)kv.h[0] * c0.x + (float)kv.h[1] * c0.y +
               (float)kv.h[2] * c0.z + (float)kv.h[3] * c0.w +
               (float)kv.h[4] * c1.x + (float)kv.h[5] * c1.y +
               (float)kv.h[6] * c1.z + (float)kv.h[7] * c1.w;
    }
    if (lane == 0) sum += (float)Krow[2048] * v[2048];
#pragma unroll
    for (int off = 32; off; off >>= 1) sum += __shfl_xor(sum, off, 64);
    return sum;
}

__global__ __launch_bounds__(TPB) void sinkhorn_persist(
    const _Float16* __restrict__ K0h, const _Float16* __restrict__ K0hT,
    float* r, float* c, unsigned* slots, unsigned* chg)
{
    const int wave = threadIdx.x >> 6, lane = threadIdx.x & 63;
    const int row = blockIdx.x * 8 + wave;
    const bool active = row < NA;
    const _Float16* KrowA = K0h  + (size_t)row * LDH;
    const _Float16* KrowB = K0hT + (size_t)row * LDH;
    __shared__ int ls_chg, ls_exit;
    float c_prev = 1.0f;

    for (int it = 0; it < ITERS; ++it) {
        if (threadIdx.x == 0) ls_chg = 0;
        // phase 1: r = 1 / (K0 c)
        if (active) {
            float s = rowdot(KrowA, c, lane);
            if (lane == 0) r[row] = 1.0f / s;
        }
        grid_barrier(&slots[2 * it]);
        // phase 2: c = 1 / (K0^T r)
        float cv = 0.0f;
        if (active) {
            float s = rowdot(KrowB, r, lane);
            cv = 1.0f / s;
            if (lane == 0) c[row] = cv;
        }
        if (active && lane == 0) {
            if (fabsf(cv - c_prev) > 1e-6f * fabsf(c_prev)) ls_chg = 1;
            c_prev = cv;
        }
        __syncthreads();
        if (threadIdx.x == 0 && ls_chg)
            __hip_atomic_fetch_or(&chg[it], 1u, __ATOMIC_RELAXED,
                                  __HIP_MEMORY_SCOPE_AGENT);
        grid_barrier(&slots[2 * it + 1]);
        if (threadIdx.x == 0)
            ls_exit = (__hip_atomic_load(&chg[it], __ATOMIC_RELAXED,
                                         __HIP_MEMORY_SCOPE_AGENT) == 0u);
        __syncthreads();
        if (ls_exit) break;
    }
}

// ---------------------------------------------------------------------------
// finalize: K = diag(r) K0 diag(c) in place (f32), P = K[:M,:N]
// ---------------------------------------------------------------------------
__global__ __launch_bounds__(256) void finalize(const float* __restrict__ r,
                                                const float* __restrict__ c,
                                                float* __restrict__ Kreg,
                                                float* __restrict__ P) {
    const int row = blockIdx.x;
    const float rs = r[row];
    for (int col = threadIdx.x; col < NA; col += 256) {
        float v = Kreg[(size_t)row * NA + col] * rs * c[col];
        Kreg[(size_t)row * NA + col] = v;
        if (row < MM && col < NN) P[(size_t)row * NN + col] = v;
    }
}

// ---------------------------------------------------------------------------
extern "C" void kernel_launch(void* const* d_in, const int* in_sizes, int n_in,
                              void* d_out, int out_size, void* d_ws, size_t ws_size,
                              hipStream_t stream) {
    const float* Q  = (const float*)d_in[0];
    const float* Rm = (const float*)d_in[1];
    const float* zp = (const float*)d_in[2];

    float* P    = (float*)d_out;
    float* Kreg = P + (size_t)MM * NN;

    ushort* Qe = (ushort*)d_out;                 // staged in P region (dead by finalize)
    ushort* Re = Qe + (size_t)2048 * LDE;

    char* ws = (char*)d_ws;
    const size_t HBYTES = 8425728;               // NA*LDH*2 rounded to 256
    _Float16* K0h  = (_Float16*)ws;
    _Float16* K0hT = (_Float16*)(ws + HBYTES);
    float* c = (float*)(ws + 2 * HBYTES);
    float* r = c + 2560;
    unsigned* ctrl = (unsigned*)(r + 2560);
    unsigned* slots = ctrl;                      // [0..255] barrier slots
    unsigned* chg   = ctrl + 256;                // [256..355] per-iter flags

    init_split<<<dim3(1026, 2), dim3(256), 0, stream>>>(Q, Rm, Qe, Re, Kreg,
                                                        K0h, K0hT, c, ctrl, zp);
    gemm_mfma<<<dim3(16, 32), dim3(256), 0, stream>>>(Qe, Re, Kreg, K0h, K0hT);
    sinkhorn_persist<<<dim3(NWG), dim3(TPB), 0, stream>>>(K0h, K0hT, r, c,
                                                          slots, chg);
    finalize<<<dim3(2049), dim3(256), 0, stream>>>(r, c, Kreg, P);
}